// Round 7
// baseline (6598.723 us; speedup 1.0000x reference)
//
#include <hip/hip_runtime.h>
#include <cstdint>
#include <cstddef>

// ---------------------------------------------------------------------------
// Round 7: recurrence -> MFMA. Rounds 4-6 proved the scalar-FMA recurrence is
// allocator-bound: the compiler caps arch VGPRs ~88 and shuffles the 128-reg
// weight array through AGPR/remat (VALUBusy 89%, 4870 cyc/step). MFMA reads
// A/B operands from VGPR *or AGPR* directly, so weight fragments live in the
// register file without per-use moves.
//   lstm_mfma: 16 batch rows/block, 8 waves; wave w owns units [16w,16w+16)
//   for all 4 gates (4 N-tiles) -> lane-local state update, no shuffles, ONE
//   barrier/step. gates = xw + h @ w_hh^T via mfma_f32_16x16x32_bf16, 3-term
//   split-bf16 (fp32-class accuracy). h in LDS as bf16 hi/lo, double-buffered,
//   rows padded to 136 (conflict-free b128). c-state in regs. xw prefetched
//   one step ahead as the MFMA C-initializer.
// GEMMs unchanged from round 6 (next target).
// ---------------------------------------------------------------------------

constexpr int Bn   = 512;
constexpr int Cn   = 271;
constexpr int Tn   = 281;
constexpr int Hn   = 128;
constexpr int NCLS = 1854;
constexpr int Gn   = 4 * Hn;    // 512

#define DEVINL __device__ __forceinline__

DEVINL float sigm(float x)       { return 1.f / (1.f + __expf(-x)); }
DEVINL float tanhf_fast(float x) { return 2.f / (1.f + __expf(-2.f * x)) - 1.f; }

typedef __attribute__((ext_vector_type(8))) short bf16x8;
typedef __attribute__((ext_vector_type(4))) float f32x4;

DEVINL short f2bf(float x) {                 // fp32 -> bf16 (RNE)
  unsigned u = __float_as_uint(x);
  unsigned r = (u + 0x7FFFu + ((u >> 16) & 1u)) >> 16;
  return (short)r;
}
DEVINL float bf2f(short h) {
  return __uint_as_float(((unsigned)(unsigned short)h) << 16);
}

// ---------------------------------------------------------------------------
// fp32 tiled GEMM (unchanged from round 6): 128x128 tile, 8x8 acc/thread.
// ---------------------------------------------------------------------------
template <int AMODE, int BMODE, int ACT, int NBIAS>
__global__ __launch_bounds__(256) void gemm_tile(
    const float* __restrict__ A, const float* __restrict__ Bm,
    const float* __restrict__ bias1, const float* __restrict__ bias2,
    float* __restrict__ Cout, int Mdim, int Ndim, int Kdim, int ldc)
{
  __shared__ __align__(16) float As[8][128];
  __shared__ __align__(16) float Bs[8][128];

  const int tid  = threadIdx.x;
  const int tx   = tid & 15;
  const int ty   = tid >> 4;
  const int row0 = blockIdx.x * 128;
  const int col0 = blockIdx.y * 128;

  float acc[8][8];
#pragma unroll
  for (int i = 0; i < 8; i++)
#pragma unroll
    for (int j = 0; j < 8; j++) acc[i][j] = 0.f;

  for (int k0 = 0; k0 < Kdim; k0 += 8) {
    if (AMODE == 0) {
      const int q  = tid >> 7;
      const int r  = tid & 127;
      const int gr = row0 + r;
      const int gk = k0 + q * 4;
      float4 v = make_float4(0.f, 0.f, 0.f, 0.f);
      if (gr < Mdim && gk + 3 < Kdim)
        v = *(const float4*)&A[(size_t)gr * Kdim + gk];
      As[q * 4 + 0][r] = v.x;
      As[q * 4 + 1][r] = v.y;
      As[q * 4 + 2][r] = v.z;
      As[q * 4 + 3][r] = v.w;
    } else {
#pragma unroll
      for (int l = 0; l < 4; l++) {
        const int e  = tid + l * 256;
        const int r  = e & 127;
        const int kk = e >> 7;
        const int gr = row0 + r;
        const int gk = k0 + kk;
        float v = 0.f;
        if (gr < Mdim && gk < Kdim) {
          const int bb = gr / Tn;
          const int tt = gr - bb * Tn;
          v = A[((size_t)bb * Cn + gk) * Tn + tt];
        }
        As[kk][r] = v;
      }
    }
#pragma unroll
    for (int l = 0; l < 4; l++) {
      const int e = tid + l * 256;
      int kk, cc;
      if (BMODE == 0) { kk = e & 7;   cc = e >> 3; }
      else            { cc = e & 127; kk = e >> 7; }
      const int gn = col0 + cc;
      const int gk = k0 + kk;
      float v = 0.f;
      if (gn < Ndim && gk < Kdim)
        v = (BMODE == 0) ? Bm[(size_t)gn * Kdim + gk]
                         : Bm[(size_t)gk * Ndim + gn];
      Bs[kk][cc] = v;
    }
    __syncthreads();
#pragma unroll
    for (int kk = 0; kk < 8; kk++) {
      const float4 a0 = *(const float4*)&As[kk][ty * 8];
      const float4 a1 = *(const float4*)&As[kk][ty * 8 + 4];
      const float4 b0 = *(const float4*)&Bs[kk][tx * 8];
      const float4 b1 = *(const float4*)&Bs[kk][tx * 8 + 4];
      const float av[8] = {a0.x, a0.y, a0.z, a0.w, a1.x, a1.y, a1.z, a1.w};
      const float bv[8] = {b0.x, b0.y, b0.z, b0.w, b1.x, b1.y, b1.z, b1.w};
#pragma unroll
      for (int i = 0; i < 8; i++)
#pragma unroll
        for (int j = 0; j < 8; j++) acc[i][j] = fmaf(av[i], bv[j], acc[i][j]);
    }
    __syncthreads();
  }
#pragma unroll
  for (int i = 0; i < 8; i++) {
    const int gr = row0 + ty * 8 + i;
    if (gr >= Mdim) continue;
    const size_t rowoff = (size_t)gr * ldc;
#pragma unroll
    for (int j = 0; j < 8; j++) {
      const int gn = col0 + tx * 8 + j;
      if (gn >= Ndim) continue;
      float v = acc[i][j];
      if (NBIAS >= 1) v += bias1[gn];
      if (NBIAS >= 2) v += bias2[gn];
      if (ACT == 1) v = tanhf_fast(v);
      Cout[rowoff + gn] = v;
    }
  }
}

// ---------------------------------------------------------------------------
// MFMA LSTM recurrence. grid (Bc/16, 2), block 512 (8 waves).
// Wave w owns units j in [16w, 16w+16) for all 4 gates; lane (qn, qd) holds
// B-frags whh[g*128+j][kt*32+qd*8+e] as bf16 hi/lo (split-bf16, 3 MFMA terms).
// A-frags: h[m=qn][kt*32+qd*8+e] from LDS bf16 hi/lo (rows padded to 136).
// C layout: row m=qd*4+reg, col=qn -> lane-local state update for 4 rows.
// xw: [2][MC][512] (b_ih+b_hh folded). hout: [MC][256].
// ---------------------------------------------------------------------------
__global__ __launch_bounds__(512, 1) void lstm_mfma(
    const float* __restrict__ xw,
    const float* __restrict__ whhf,
    const float* __restrict__ whhb,
    float* __restrict__ hout, int MC)
{
  const int dir = blockIdx.y;
  const int rb  = blockIdx.x * 16;        // local batch-row base
  const int tid = threadIdx.x;
  const int wv  = tid >> 6;               // wave 0..7
  const int ln  = tid & 63;
  const int qn  = ln & 15;                // tile col (n) == A row (m)
  const int qd  = ln >> 4;                // quad 0..3
  const int j   = wv * 16 + qn;           // unit column 0..127
  const float* __restrict__ whh = dir ? whhb : whhf;
  const float* __restrict__ xwd = xw + (size_t)dir * MC * Gn;

  __shared__ short hhi[2][16 * 136];
  __shared__ short hlo[2][16 * 136];

  for (int i = tid; i < 16 * 136; i += 512) {
    hhi[0][i] = 0; hhi[1][i] = 0; hlo[0][i] = 0; hlo[1][i] = 0;
  }

  // B-fragments (weights), resident for all 281 steps
  bf16x8 whi[4][4], wlo[4][4];
#pragma unroll
  for (int g = 0; g < 4; g++)
#pragma unroll
    for (int kt = 0; kt < 4; kt++) {
      const float* wp = &whh[(size_t)(g * Hn + j) * Hn + kt * 32 + qd * 8];
      const float4 v0 = *(const float4*)wp;
      const float4 v1 = *(const float4*)(wp + 4);
      const float xv[8] = {v0.x, v0.y, v0.z, v0.w, v1.x, v1.y, v1.z, v1.w};
#pragma unroll
      for (int e = 0; e < 8; e++) {
        const short h = f2bf(xv[e]);
        whi[g][kt][e] = h;
        wlo[g][kt][e] = f2bf(xv[e] - bf2f(h));
      }
    }

  float c[4] = {0.f, 0.f, 0.f, 0.f};
  float xwcur[4][4];                       // [gate][reg]
  {
    const int t0 = dir ? (Tn - 1) : 0;
#pragma unroll
    for (int g = 0; g < 4; g++)
#pragma unroll
      for (int r = 0; r < 4; r++)
        xwcur[g][r] = xwd[((size_t)(rb + qd * 4 + r) * Tn + t0) * Gn + g * Hn + j];
  }
  __syncthreads();

  for (int s = 0; s < Tn; s++) {
    const int p  = s & 1;
    const int t  = dir ? (Tn - 1 - s) : s;
    const int sn = (s + 1 < Tn) ? s + 1 : s;
    const int tn_ = dir ? (Tn - 1 - sn) : sn;

    // prefetch next step's xw (C-initializer)
    float xwn[4][4];
#pragma unroll
    for (int g = 0; g < 4; g++)
#pragma unroll
      for (int r = 0; r < 4; r++)
        xwn[g][r] = xwd[((size_t)(rb + qd * 4 + r) * Tn + tn_) * Gn + g * Hn + j];

    // A-fragments from LDS (h_{t-1})
    bf16x8 ahi[4], alo[4];
#pragma unroll
    for (int kt = 0; kt < 4; kt++) {
      const int off = qn * 136 + kt * 32 + qd * 8;
      ahi[kt] = *(const bf16x8*)&hhi[p][off];
      alo[kt] = *(const bf16x8*)&hlo[p][off];
    }

    // gates = xw + h @ whh^T  (3-term split-bf16)
    f32x4 acc[4];
#pragma unroll
    for (int g = 0; g < 4; g++) {
      f32x4 a;
      a[0] = xwcur[g][0]; a[1] = xwcur[g][1];
      a[2] = xwcur[g][2]; a[3] = xwcur[g][3];
      acc[g] = a;
    }
#pragma unroll
    for (int kt = 0; kt < 4; kt++)
#pragma unroll
      for (int g = 0; g < 4; g++) {
        acc[g] = __builtin_amdgcn_mfma_f32_16x16x32_bf16(ahi[kt], whi[g][kt], acc[g], 0, 0, 0);
        acc[g] = __builtin_amdgcn_mfma_f32_16x16x32_bf16(ahi[kt], wlo[g][kt], acc[g], 0, 0, 0);
        acc[g] = __builtin_amdgcn_mfma_f32_16x16x32_bf16(alo[kt], whi[g][kt], acc[g], 0, 0, 0);
      }

    // state update: lane owns (m = qd*4+r, unit j), gate order i,f,g,o
#pragma unroll
    for (int r = 0; r < 4; r++) {
      const float iv = sigm(acc[0][r]);
      const float fv = sigm(acc[1][r]);
      const float gv = tanhf_fast(acc[2][r]);
      const float ov = sigm(acc[3][r]);
      c[r] = fv * c[r] + iv * gv;
      const float hv = ov * tanhf_fast(c[r]);
      const int m = qd * 4 + r;
      const short hh = f2bf(hv);
      hhi[p ^ 1][m * 136 + j] = hh;
      hlo[p ^ 1][m * 136 + j] = f2bf(hv - bf2f(hh));
      hout[((size_t)(rb + m) * Tn + t) * 256 + dir * Hn + j] = hv;
    }
#pragma unroll
    for (int g = 0; g < 4; g++)
#pragma unroll
      for (int r = 0; r < 4; r++) xwcur[g][r] = xwn[g][r];
    __syncthreads();
  }
}

// ---------------------------------------------------------------------------
// a[m] = u[m][0:256] . v[0:256] — one wave per row.
// ---------------------------------------------------------------------------
__global__ __launch_bounds__(256) void dot_v_kernel(
    const float* __restrict__ u, const float* __restrict__ v,
    float* __restrict__ a, int MC)
{
  const int lane = threadIdx.x & 63;
  const int row  = blockIdx.x * 4 + (threadIdx.x >> 6);
  if (row >= MC) return;
  const float4 uv = ((const float4*)(u + (size_t)row * 256))[lane];
  const float4 vv = ((const float4*)v)[lane];
  float p = uv.x * vv.x + uv.y * vv.y + uv.z * vv.z + uv.w * vv.w;
#pragma unroll
  for (int off = 32; off > 0; off >>= 1) p += __shfl_down(p, off);
  if (lane == 0) a[row] = p;
}

// ---------------------------------------------------------------------------
// softmax over T + pooling (chunk-local).
// ---------------------------------------------------------------------------
__global__ __launch_bounds__(256) void attn_pool(
    const float* __restrict__ a, const float* __restrict__ h1,
    float* __restrict__ wout)
{
  const int b    = blockIdx.x;
  const int tid  = threadIdx.x;
  const int lane = tid & 63;
  const int wid  = tid >> 6;
  __shared__ float sa[Tn];
  __shared__ float red[8];

  float lmax = -3.4e38f;
  for (int t = tid; t < Tn; t += 256) {
    const float x = a[(size_t)b * Tn + t];
    sa[t] = x;
    lmax  = fmaxf(lmax, x);
  }
#pragma unroll
  for (int off = 1; off < 64; off <<= 1) lmax = fmaxf(lmax, __shfl_xor(lmax, off));
  if (lane == 0) red[wid] = lmax;
  __syncthreads();
  const float bmax = fmaxf(fmaxf(red[0], red[1]), fmaxf(red[2], red[3]));

  float lsum = 0.f;
  for (int t = tid; t < Tn; t += 256) {
    const float e = __expf(sa[t] - bmax);
    sa[t] = e;
    lsum += e;
  }
#pragma unroll
  for (int off = 1; off < 64; off <<= 1) lsum += __shfl_xor(lsum, off);
  if (lane == 0) red[4 + wid] = lsum;
  __syncthreads();
  const float inv = 1.f / (red[4] + red[5] + red[6] + red[7]);

  float acc = 0.f;
  const float* hb = h1 + (size_t)b * Tn * 256 + tid;
  for (int t = 0; t < Tn; t++) acc += sa[t] * hb[(size_t)t * 256];
  wout[(size_t)b * 256 + tid] = acc * inv;
}

// ---------------------------------------------------------------------------
extern "C" void kernel_launch(void* const* d_in, const int* in_sizes, int n_in,
                              void* d_out, int out_size, void* d_ws, size_t ws_size,
                              hipStream_t stream)
{
  const float* X      = (const float*)d_in[0];
  const float* w_ih0f = (const float*)d_in[1];
  const float* w_hh0f = (const float*)d_in[2];
  const float* b_ih0f = (const float*)d_in[3];
  const float* b_hh0f = (const float*)d_in[4];
  const float* w_ih0b = (const float*)d_in[5];
  const float* w_hh0b = (const float*)d_in[6];
  const float* b_ih0b = (const float*)d_in[7];
  const float* b_hh0b = (const float*)d_in[8];
  const float* w_ih1f = (const float*)d_in[9];
  const float* w_hh1f = (const float*)d_in[10];
  const float* b_ih1f = (const float*)d_in[11];
  const float* b_hh1f = (const float*)d_in[12];
  const float* w_ih1b = (const float*)d_in[13];
  const float* w_hh1b = (const float*)d_in[14];
  const float* b_ih1b = (const float*)d_in[15];
  const float* b_hh1b = (const float*)d_in[16];
  const float* att_W  = (const float*)d_in[17];
  const float* att_v  = (const float*)d_in[18];
  const float* head_W = (const float*)d_in[19];
  const float* head_b = (const float*)d_in[20];

  // largest chunk size fitting ws_size (deterministic across calls)
  int Bc = 16;
  {
    const int cands[6] = {512, 256, 128, 64, 32, 16};
    for (int i = 0; i < 6; i++) {
      const size_t mc   = (size_t)cands[i] * Tn;
      const size_t need = 4ull * ((size_t)512 * 256 + mc * 1537);
      if (need <= ws_size) { Bc = cands[i]; break; }
    }
  }
  const size_t MCs = (size_t)Bc * Tn;
  const int    MC  = (int)MCs;

  float* wgt = (float*)d_ws;               // [512][256] persistent
  float* xwc = wgt + (size_t)512 * 256;    // [2][MC][512]
  float* h0c = xwc + 2 * MCs * Gn;         // [MC][256]
  float* h1c = h0c + MCs * 256;            // [MC][256]
  float* ac  = h1c + MCs * 256;            // [MC]
  float* u   = xwc;                        // reuse (xw dead by phase 5)

  const dim3 blk(256);
  const int  mt = (MC + 127) / 128;
  const dim3 gXW(mt, Gn / 128);            // (., 4)
  const dim3 gU(mt, 256 / 128);            // (., 2)
  const int  nch = Bn / Bc;

  for (int ch = 0; ch < nch; ch++) {
    const float* Xc   = X + (size_t)ch * Bc * Cn * Tn;
    float*       wgtc = wgt + (size_t)ch * Bc * 256;

    // 1) layer-0 input projections (transpose fused), both biases folded
    gemm_tile<1, 0, 0, 2><<<gXW, blk, 0, stream>>>(Xc, w_ih0f, b_ih0f, b_hh0f,
                                                   xwc, MC, Gn, Cn, Gn);
    gemm_tile<1, 0, 0, 2><<<gXW, blk, 0, stream>>>(Xc, w_ih0b, b_ih0b, b_hh0b,
                                                   xwc + MCs * Gn, MC, Gn, Cn, Gn);
    // 2) layer-0 recurrence (MFMA)
    lstm_mfma<<<dim3(Bc / 16, 2), dim3(512), 0, stream>>>(xwc, w_hh0f, w_hh0b, h0c, MC);
    // 3) layer-1 input projections
    gemm_tile<0, 0, 0, 2><<<gXW, blk, 0, stream>>>(h0c, w_ih1f, b_ih1f, b_hh1f,
                                                   xwc, MC, Gn, 256, Gn);
    gemm_tile<0, 0, 0, 2><<<gXW, blk, 0, stream>>>(h0c, w_ih1b, b_ih1b, b_hh1b,
                                                   xwc + MCs * Gn, MC, Gn, 256, Gn);
    // 4) layer-1 recurrence (MFMA)
    lstm_mfma<<<dim3(Bc / 16, 2), dim3(512), 0, stream>>>(xwc, w_hh1f, w_hh1b, h1c, MC);
    // 5) u = tanh(h1 @ att_W)
    gemm_tile<0, 1, 1, 0><<<gU, blk, 0, stream>>>(h1c, att_W, nullptr, nullptr,
                                                  u, MC, 256, 256, 256);
    // 6) a = u . att_v
    dot_v_kernel<<<dim3((MC + 3) / 4), blk, 0, stream>>>(u, att_v, ac, MC);
    // 7) softmax + pooling into this chunk's wgt slice
    attn_pool<<<dim3(Bc), blk, 0, stream>>>(ac, h1c, wgtc);
  }
  // 8) head
  gemm_tile<0, 0, 0, 1><<<dim3((Bn + 127) / 128, (NCLS + 127) / 128), blk, 0, stream>>>(
      wgt, head_W, head_b, nullptr, (float*)d_out, Bn, NCLS, 256, NCLS);
}